// Round 1
// baseline (325.324 us; speedup 1.0000x reference)
//
#include <hip/hip_runtime.h>
#include <hip/hip_bf16.h>
#include <math.h>

// Problem constants
#define BATCH   8
#define IN_CH   256     // c
#define NDIM    256     // n (NUM_COEFFS*REPEAT)
#define OUT_CH  256     // d
#define L_SEQ   8192

// ---------------------------------------------------------------------------
// Kernel 0: W1[n][c] = exp(log_dt[n]) * B[n][c]
// ---------------------------------------------------------------------------
__global__ void prep_w1(const float* __restrict__ B,
                        const float* __restrict__ log_dt,
                        float* __restrict__ W1) {
    int idx = blockIdx.x * 256 + threadIdx.x;   // 0..65535
    int n = idx >> 8;
    W1[idx] = B[idx] * expf(log_dt[n]);
}

// ---------------------------------------------------------------------------
// Tiled fp32 GEMM:  O[b][m][l] = sum_k W[m][k] * X[b][k][l]
// M=K=256, L=8192.  MT=64, LT=256, KT=32, 256 threads, 8x8 microtile.
// ---------------------------------------------------------------------------
#define MT 64
#define LT 256
#define KT 32

__global__ __launch_bounds__(256) void gemm_kernel(
        const float* __restrict__ W,   // [256][256] row-major, k contiguous
        const float* __restrict__ X,   // [B][256][L]
        float* __restrict__ O)         // [B][256][L]
{
    __shared__ float Ws[KT][MT];   // [k][m]
    __shared__ float Xs[KT][LT];   // [k][l]

    const int t  = threadIdx.x;
    const int l0 = blockIdx.x * LT;
    const int m0 = blockIdx.y * MT;
    const int b  = blockIdx.z;
    const float* Xb = X + (size_t)b * IN_CH * L_SEQ;

    const int tm = t >> 5;   // 0..7  -> m microrow
    const int tl = t & 31;   // 0..31 -> l microcol

    float acc[8][8];
#pragma unroll
    for (int i = 0; i < 8; ++i)
#pragma unroll
        for (int j = 0; j < 8; ++j) acc[i][j] = 0.0f;

    for (int k0 = 0; k0 < 256; k0 += KT) {
        // ---- load W tile (64m x 32k), transpose into Ws[k][m]
        {
            int m  = t >> 2;          // 0..63
            int kk = (t & 3) * 8;     // 0,8,16,24
            const float* src = W + (size_t)(m0 + m) * 256 + k0 + kk;
            float4 a  = *(const float4*)src;
            float4 b4 = *(const float4*)(src + 4);
            Ws[kk + 0][m] = a.x;  Ws[kk + 1][m] = a.y;
            Ws[kk + 2][m] = a.z;  Ws[kk + 3][m] = a.w;
            Ws[kk + 4][m] = b4.x; Ws[kk + 5][m] = b4.y;
            Ws[kk + 6][m] = b4.z; Ws[kk + 7][m] = b4.w;
        }
        // ---- load X tile (32k x 256l), coalesced float4
#pragma unroll
        for (int i = 0; i < 8; ++i) {
            int flat = t + i * 256;        // float4 index, 0..2047
            int r  = flat >> 6;            // 0..31
            int c4 = flat & 63;            // 0..63
            float4 v = *(const float4*)(Xb + (size_t)(k0 + r) * L_SEQ + l0 + c4 * 4);
            *(float4*)&Xs[r][c4 * 4] = v;
        }
        __syncthreads();

#pragma unroll
        for (int k = 0; k < KT; ++k) {
            float4 w0 = *(const float4*)&Ws[k][tm * 8];
            float4 w1 = *(const float4*)&Ws[k][tm * 8 + 4];
            float4 x0 = *(const float4*)&Xs[k][tl * 8];
            float4 x1 = *(const float4*)&Xs[k][tl * 8 + 4];
            float wv[8] = {w0.x, w0.y, w0.z, w0.w, w1.x, w1.y, w1.z, w1.w};
            float xv[8] = {x0.x, x0.y, x0.z, x0.w, x1.x, x1.y, x1.z, x1.w};
#pragma unroll
            for (int i = 0; i < 8; ++i)
#pragma unroll
                for (int j = 0; j < 8; ++j)
                    acc[i][j] += wv[i] * xv[j];
        }
        __syncthreads();
    }

    // ---- store 8x8 microtile
    float* Ob = O + (size_t)b * 256 * L_SEQ + (size_t)m0 * L_SEQ + l0;
#pragma unroll
    for (int i = 0; i < 8; ++i) {
        float* row = Ob + (size_t)(tm * 8 + i) * L_SEQ + tl * 8;
        float4 o0 = {acc[i][0], acc[i][1], acc[i][2], acc[i][3]};
        float4 o1 = {acc[i][4], acc[i][5], acc[i][6], acc[i][7]};
        *(float4*)row       = o0;
        *((float4*)row + 1) = o1;
    }
}

// ---------------------------------------------------------------------------
// Kernel 2: complex linear scan, in place on XY[b][n][:]
//   s[l] = lambda*s[l-1] + xb[l],  y[l] = Re(s[l])
// One 64-thread block per (b,n). 64 chunks x 128. Wave-level carry scan.
// ---------------------------------------------------------------------------
__global__ __launch_bounds__(64) void scan_kernel(
        const float* __restrict__ A,        // [256][2] (log_A_real, A_imag)
        const float* __restrict__ log_dt,   // [256]
        float* __restrict__ XY)             // [B][256][L], in place
{
    __shared__ float buf[64 * 129];   // 64 chunks, stride 129 (conflict-free scan)
    const int lane = threadIdx.x;
    const int n = blockIdx.x;
    const int b = blockIdx.y;
    float* base = XY + ((size_t)b * 256 + n) * L_SEQ;

    // ---- stage in (coalesced float4 -> padded LDS)
#pragma unroll
    for (int k = 0; k < 32; ++k) {
        int e = (k * 64 + lane) * 4;          // element index
        float4 v = *(const float4*)(base + e);
        int chunk = e >> 7, off = e & 127;
        float* d = &buf[chunk * 129 + off];
        d[0] = v.x; d[1] = v.y; d[2] = v.z; d[3] = v.w;
    }
    __syncthreads();

    // ---- lambda from A, log_dt
    float la_r = A[2 * n], a_im = A[2 * n + 1];
    float dt   = expf(log_dt[n]);
    float dAr  = -dt * log1pf(expf(la_r));    // dt * softplus(log_A_real), negated
    float dAi  = dt * a_im;
    float edr  = expf(dAr);
    float lr = edr * cosf(dAi);
    float li = edr * sinf(dAi);

    // ---- local scan (zero init) for chunk summary
    float sr = 0.f, si = 0.f;
    float* my = &buf[lane * 129];
    for (int tt = 0; tt < 128; ++tt) {
        float v  = my[tt];
        float nr = lr * sr - li * si + v;
        float ni = lr * si + li * sr;
        sr = nr; si = ni;
    }

    // ---- chunk multiplier m = lambda^128 (closed form)
    float er = expf(dAr * 128.0f);
    float ph = dAi * 128.0f;
    float mr = er * cosf(ph), mi = er * sinf(ph);

    // ---- inclusive Hillis-Steele scan of chunk states across the wave
    float vr = sr, vi = si;
#pragma unroll
    for (int d = 1; d < 64; d <<= 1) {
        float ur = __shfl_up(vr, (unsigned)d);
        float ui = __shfl_up(vi, (unsigned)d);
        if (lane >= d) {
            float tr = mr * ur - mi * ui + vr;
            float ti = mr * ui + mi * ur + vi;
            vr = tr; vi = ti;
        }
        float m2r = mr * mr - mi * mi;
        float m2i = 2.0f * mr * mi;
        mr = m2r; mi = m2i;
    }
    float cr = __shfl_up(vr, 1u);
    float ci = __shfl_up(vi, 1u);
    if (lane == 0) { cr = 0.f; ci = 0.f; }

    // ---- rescan with carry, write y = Re(s) back into LDS
    sr = cr; si = ci;
    for (int tt = 0; tt < 128; ++tt) {
        float v  = my[tt];
        float nr = lr * sr - li * si + v;
        float ni = lr * si + li * sr;
        sr = nr; si = ni;
        my[tt] = nr;
    }
    __syncthreads();

    // ---- stage out (padded LDS -> coalesced float4)
#pragma unroll
    for (int k = 0; k < 32; ++k) {
        int e = (k * 64 + lane) * 4;
        int chunk = e >> 7, off = e & 127;
        float* s = &buf[chunk * 129 + off];
        float4 v = {s[0], s[1], s[2], s[3]};
        *(float4*)(base + e) = v;
    }
}

// ---------------------------------------------------------------------------
// Launch
// ---------------------------------------------------------------------------
extern "C" void kernel_launch(void* const* d_in, const int* in_sizes, int n_in,
                              void* d_out, int out_size, void* d_ws, size_t ws_size,
                              hipStream_t stream) {
    const float* x      = (const float*)d_in[0];  // [8][256][8192]
    const float* A      = (const float*)d_in[1];  // [256][2]
    const float* B      = (const float*)d_in[2];  // [256][256]
    const float* log_dt = (const float*)d_in[3];  // [256]
    const float* C      = (const float*)d_in[4];  // [256][256]
    float* out = (float*)d_out;                   // [8][256][8192]

    // ws layout: W1 (256 KB) | xb/y buffer (64 MB, scan runs in place)
    float* W1 = (float*)d_ws;
    float* xb = (float*)((char*)d_ws + 256 * 1024);

    // 0) W1 = dt[n] * B[n][c]
    prep_w1<<<256, 256, 0, stream>>>(B, log_dt, W1);

    // 1) xb = W1 @ x  (per batch)
    gemm_kernel<<<dim3(L_SEQ / LT, 256 / MT, BATCH), 256, 0, stream>>>(W1, x, xb);

    // 2) y = causal conv via complex linear recurrence (in place on xb)
    scan_kernel<<<dim3(256, BATCH), 64, 0, stream>>>(A, log_dt, xb);

    // 3) out = C @ y  (per batch)
    gemm_kernel<<<dim3(L_SEQ / LT, 256 / MT, BATCH), 256, 0, stream>>>(C, xb, out);
}

// Round 2
// 203.711 us; speedup vs baseline: 1.5970x; 1.5970x over previous
//
#include <hip/hip_runtime.h>
#include <hip/hip_bf16.h>
#include <math.h>

#define BATCH 8
#define L_SEQ 8192
#define KD    256   // shared contraction dim for both GEMMs (c / n)

typedef __attribute__((ext_vector_type(8))) short bf16x8;
typedef __attribute__((ext_vector_type(4))) float f32x4;

__device__ __forceinline__ void async_ld16(const __hip_bfloat16* g, __hip_bfloat16* l) {
    __builtin_amdgcn_global_load_lds(
        (const __attribute__((address_space(1))) unsigned int*)g,
        (__attribute__((address_space(3))) unsigned int*)l, 16, 0, 0);
}

// ---------------------------------------------------------------------------
// prep: W1bf[n][c] = bf16(B[n][c] * exp(log_dt[n]));  Cbf[d][n] = bf16(C[d][n])
// ---------------------------------------------------------------------------
__global__ void prep(const float* __restrict__ B, const float* __restrict__ logdt,
                     const float* __restrict__ C,
                     __hip_bfloat16* __restrict__ W1bf, __hip_bfloat16* __restrict__ Cbf) {
    int i = blockIdx.x * 256 + threadIdx.x;        // 0..65535
    W1bf[i] = __float2bfloat16(B[i] * expf(logdt[i >> 8]));
    Cbf[i]  = __float2bfloat16(C[i]);
}

// ---------------------------------------------------------------------------
// transpose+cast: x[b][c][l] fp32 -> x_t[b][l][c] bf16.  64x64 tiles.
// ---------------------------------------------------------------------------
__global__ __launch_bounds__(256) void transpose_cast(
        const float* __restrict__ X, __hip_bfloat16* __restrict__ XT) {
    __shared__ float tile[64][65];
    const int t = threadIdx.x;
    const int l0 = blockIdx.x * 64, c0 = blockIdx.y * 64, b = blockIdx.z;
    const float* Xb = X + (size_t)b * KD * L_SEQ;
    __hip_bfloat16* Tb = XT + (size_t)b * L_SEQ * KD;

    int cl = t >> 4;          // 0..15
    int l4 = (t & 15) * 4;    // 0..60
#pragma unroll
    for (int i = 0; i < 4; ++i) {
        int c = cl + 16 * i;
        float4 v = *(const float4*)(Xb + (size_t)(c0 + c) * L_SEQ + l0 + l4);
        tile[c][l4 + 0] = v.x; tile[c][l4 + 1] = v.y;
        tile[c][l4 + 2] = v.z; tile[c][l4 + 3] = v.w;
    }
    __syncthreads();

    int ll = t & 63;
    int c8g = t >> 6;         // 0..3
#pragma unroll
    for (int h = 0; h < 2; ++h) {
        int c8 = (c8g + 4 * h) * 8;
        union { __hip_bfloat16 s[8]; uint4 v; } pk;
#pragma unroll
        for (int j = 0; j < 8; ++j) pk.s[j] = __float2bfloat16(tile[c8 + j][ll]);
        *(uint4*)(Tb + (size_t)(l0 + ll) * KD + c0 + c8) = pk.v;
    }
}

// ---------------------------------------------------------------------------
// MFMA GEMM:  D[b][row][col] = sum_k A[row][k] * B[col][k]   (both k-contig bf16)
// 128x128 tile, BK=64, 256 thr = 4 waves (2x2), 4x4 of 16x16x32 MFMA per wave.
// Fragment-order LDS staging via global_load_lds(16B).
// ---------------------------------------------------------------------------
template <typename OutT>
__global__ __launch_bounds__(256) void mfma_gemm(
        const __hip_bfloat16* __restrict__ Ag,
        const __hip_bfloat16* __restrict__ Bg,
        OutT* __restrict__ Dg,
        int nrows, int ncols, long Abstride, long Bbstride)
{
    __shared__ __hip_bfloat16 Abuf[16 * 512];   // 16 KB: 16 blocks x 64 lanes x 8 bf16
    __shared__ __hip_bfloat16 Bbuf[16 * 512];

    const int t = threadIdx.x, lane = t & 63, wave = t >> 6;
    const int wr = wave >> 1, wc = wave & 1;
    const int row0 = blockIdx.y * 128, col0 = blockIdx.x * 128;
    const int lm = lane & 15, lq = lane >> 4;
    const __hip_bfloat16* Ab = Ag + (size_t)blockIdx.z * Abstride;
    const __hip_bfloat16* Bb = Bg + (size_t)blockIdx.z * Bbstride;
    OutT* Db = Dg + (size_t)blockIdx.z * (size_t)nrows * ncols;

    f32x4 acc[4][4];
#pragma unroll
    for (int i = 0; i < 4; ++i)
#pragma unroll
        for (int j = 0; j < 4; ++j) acc[i][j] = {0.f, 0.f, 0.f, 0.f};

    for (int k0 = 0; k0 < KD; k0 += 64) {
        // stage 32 x 1KB fragment blocks; each wave issues 8 async loads
#pragma unroll
        for (int i = 0; i < 8; ++i) {
            int idx = wave * 8 + i;
            if (idx < 16) {
                int rt = idx >> 1, s = idx & 1;
                const __hip_bfloat16* g =
                    Ab + (size_t)(row0 + rt * 16 + lm) * KD + k0 + s * 32 + lq * 8;
                async_ld16(g, &Abuf[idx * 512 + lane * 8]);
            } else {
                int jb = idx - 16, ct = jb >> 1, s = jb & 1;
                const __hip_bfloat16* g =
                    Bb + (size_t)(col0 + ct * 16 + lm) * KD + k0 + s * 32 + lq * 8;
                async_ld16(g, &Bbuf[jb * 512 + lane * 8]);
            }
        }
        __syncthreads();
#pragma unroll
        for (int s = 0; s < 2; ++s) {
            bf16x8 af[4], bfr[4];
#pragma unroll
            for (int i = 0; i < 4; ++i)
                af[i] = *(const bf16x8*)&Abuf[((wr * 4 + i) * 2 + s) * 512 + lane * 8];
#pragma unroll
            for (int j = 0; j < 4; ++j)
                bfr[j] = *(const bf16x8*)&Bbuf[((wc * 4 + j) * 2 + s) * 512 + lane * 8];
#pragma unroll
            for (int i = 0; i < 4; ++i)
#pragma unroll
                for (int j = 0; j < 4; ++j)
                    acc[i][j] = __builtin_amdgcn_mfma_f32_16x16x32_bf16(
                        af[i], bfr[j], acc[i][j], 0, 0, 0);
        }
        __syncthreads();
    }

    // epilogue: D row = row0+wr*64+i*16+lq*4+r, col = col0+wc*64+j*16+lm
#pragma unroll
    for (int i = 0; i < 4; ++i) {
        int r0 = row0 + wr * 64 + i * 16 + lq * 4;
#pragma unroll
        for (int j = 0; j < 4; ++j) {
            int c = col0 + wc * 64 + j * 16 + lm;
#pragma unroll
            for (int r = 0; r < 4; ++r)
                Db[(size_t)(r0 + r) * ncols + c] = (OutT)acc[i][j][r];
        }
    }
}

// ---------------------------------------------------------------------------
// Scan over l in [l][n] layout.  lambda_n = exp(dt*(-softplus(logAre) + i*Aim))
// Pass A: per-(b,seg) local scan (zero init) -> segment summary state
// Pass B: per-(b,n) wave scan of 64 summaries -> exclusive carries (in place)
// Pass C: re-scan with carry init, write y = Re(s) in place (bf16)
// ---------------------------------------------------------------------------
__device__ __forceinline__ void lambda_of(const float* A, const float* logdt, int n,
                                          float& lr, float& li, float& dAr, float& dAi) {
    float dt = expf(logdt[n]);
    dAr = -dt * log1pf(expf(A[2 * n]));
    dAi = dt * A[2 * n + 1];
    float e = expf(dAr);
    lr = e * cosf(dAi);
    li = e * sinf(dAi);
}

__global__ __launch_bounds__(256) void scan_sum(
        const __hip_bfloat16* __restrict__ xb, const float* __restrict__ A,
        const float* __restrict__ logdt, float2* __restrict__ sums) {
    const int n = threadIdx.x, seg = blockIdx.x, b = blockIdx.y;
    float lr, li, dAr, dAi;
    lambda_of(A, logdt, n, lr, li, dAr, dAi);
    const __hip_bfloat16* p = xb + ((size_t)b * L_SEQ + seg * 128) * KD + n;
    float sr = 0.f, si = 0.f;
#pragma unroll 4
    for (int l = 0; l < 128; ++l) {
        float v = __bfloat162float(p[(size_t)l * KD]);
        float nr = lr * sr - li * si + v;
        float ni = lr * si + li * sr;
        sr = nr; si = ni;
    }
    sums[((size_t)b * KD + n) * 64 + seg] = make_float2(sr, si);
}

__global__ __launch_bounds__(64) void scan_carry(
        const float* __restrict__ A, const float* __restrict__ logdt,
        float2* __restrict__ sums) {
    const int lane = threadIdx.x;                 // = segment
    const int b = blockIdx.x >> 8, n = blockIdx.x & 255;
    float lr, li, dAr, dAi;
    lambda_of(A, logdt, n, lr, li, dAr, dAi);
    // m = lambda^128 closed form
    float er = expf(dAr * 128.0f), ph = dAi * 128.0f;
    float mr = er * cosf(ph), mi = er * sinf(ph);

    float2 s = sums[((size_t)b * KD + n) * 64 + lane];
    float vr = s.x, vi = s.y;
#pragma unroll
    for (int d = 1; d < 64; d <<= 1) {
        float ur = __shfl_up(vr, (unsigned)d);
        float ui = __shfl_up(vi, (unsigned)d);
        if (lane >= d) {
            float tr = mr * ur - mi * ui + vr;
            float ti = mr * ui + mi * ur + vi;
            vr = tr; vi = ti;
        }
        float m2r = mr * mr - mi * mi;
        float m2i = 2.0f * mr * mi;
        mr = m2r; mi = m2i;
    }
    float cr = __shfl_up(vr, 1u), ci = __shfl_up(vi, 1u);
    if (lane == 0) { cr = 0.f; ci = 0.f; }
    sums[((size_t)b * KD + n) * 64 + lane] = make_float2(cr, ci);
}

__global__ __launch_bounds__(256) void scan_apply(
        __hip_bfloat16* __restrict__ xb, const float* __restrict__ A,
        const float* __restrict__ logdt, const float2* __restrict__ sums) {
    const int n = threadIdx.x, seg = blockIdx.x, b = blockIdx.y;
    float lr, li, dAr, dAi;
    lambda_of(A, logdt, n, lr, li, dAr, dAi);
    float2 c = sums[((size_t)b * KD + n) * 64 + seg];
    float sr = c.x, si = c.y;
    __hip_bfloat16* p = xb + ((size_t)b * L_SEQ + seg * 128) * KD + n;
#pragma unroll 4
    for (int l = 0; l < 128; ++l) {
        float v = __bfloat162float(p[(size_t)l * KD]);
        float nr = lr * sr - li * si + v;
        float ni = lr * si + li * sr;
        sr = nr; si = ni;
        p[(size_t)l * KD] = __float2bfloat16(nr);
    }
}

// ---------------------------------------------------------------------------
// Launch
// ---------------------------------------------------------------------------
extern "C" void kernel_launch(void* const* d_in, const int* in_sizes, int n_in,
                              void* d_out, int out_size, void* d_ws, size_t ws_size,
                              hipStream_t stream) {
    const float* x      = (const float*)d_in[0];  // [8][256][8192]
    const float* A      = (const float*)d_in[1];  // [256][2]
    const float* B      = (const float*)d_in[2];  // [256][256]
    const float* log_dt = (const float*)d_in[3];  // [256]
    const float* C      = (const float*)d_in[4];  // [256][256]
    float* out = (float*)d_out;                   // [8][256][8192]

    char* ws = (char*)d_ws;
    __hip_bfloat16* W1bf = (__hip_bfloat16*)(ws);                 // 128 KB
    __hip_bfloat16* Cbf  = (__hip_bfloat16*)(ws + (128 << 10));   // 128 KB
    float2*         sums = (float2*)(ws + (256 << 10));           // 1 MB
    __hip_bfloat16* x_t  = (__hip_bfloat16*)(ws + (1280 << 10));  // 32 MB
    __hip_bfloat16* xb_t = (__hip_bfloat16*)(ws + (1280 << 10) + ((size_t)32 << 20)); // 32 MB

    const long PB = (long)L_SEQ * KD;   // per-batch elements

    prep<<<256, 256, 0, stream>>>(B, log_dt, C, W1bf, Cbf);
    transpose_cast<<<dim3(L_SEQ / 64, KD / 64, BATCH), 256, 0, stream>>>(x, x_t);
    // GEMM1: xb_t[b][l][n] = sum_c x_t[b][l][c] * W1bf[n][c]
    mfma_gemm<__hip_bfloat16><<<dim3(KD / 128, L_SEQ / 128, BATCH), 256, 0, stream>>>(
        x_t, W1bf, xb_t, L_SEQ, KD, PB, 0);
    // scan along l (in place on xb_t)
    scan_sum<<<dim3(64, BATCH), 256, 0, stream>>>(xb_t, A, log_dt, sums);
    scan_carry<<<BATCH * KD, 64, 0, stream>>>(A, log_dt, sums);
    scan_apply<<<dim3(64, BATCH), 256, 0, stream>>>(xb_t, A, log_dt, sums);
    // GEMM2: out[b][d][l] = sum_n Cbf[d][n] * y_t[b][l][n]
    mfma_gemm<float><<<dim3(L_SEQ / 128, KD / 128, BATCH), 256, 0, stream>>>(
        Cbf, xb_t, out, KD, L_SEQ, 0, PB);
}

// Round 4
// 180.924 us; speedup vs baseline: 1.7981x; 1.1259x over previous
//
#include <hip/hip_runtime.h>
#include <hip/hip_bf16.h>
#include <math.h>

#define BATCH 8
#define L_SEQ 8192
#define KD    256   // contraction dim for both GEMMs (c / n)

typedef __attribute__((ext_vector_type(8))) short bf16x8;
typedef __attribute__((ext_vector_type(4))) float f32x4;

__device__ __forceinline__ void async_ld16(const __hip_bfloat16* g, __hip_bfloat16* l) {
    __builtin_amdgcn_global_load_lds(
        (const __attribute__((address_space(1))) unsigned int*)g,
        (__attribute__((address_space(3))) unsigned int*)l, 16, 0, 0);
}

// ---------------------------------------------------------------------------
// prep: W1bf[n][c] = bf16(B[n][c]*dt[n]); Cbf[d][n] = bf16(C[d][n]);
// lamtab[n*4+0] = lambda, +1 = lambda^16, +2 = lambda^128, +3 = (dAr, dAi)
// ---------------------------------------------------------------------------
__global__ void prep(const float* __restrict__ B, const float* __restrict__ logdt,
                     const float* __restrict__ C, const float* __restrict__ A,
                     __hip_bfloat16* __restrict__ W1bf, __hip_bfloat16* __restrict__ Cbf,
                     float2* __restrict__ lamtab) {
    int i = blockIdx.x * 256 + threadIdx.x;
    W1bf[i] = __float2bfloat16(B[i] * expf(logdt[i >> 8]));
    Cbf[i]  = __float2bfloat16(C[i]);
    if (blockIdx.x == 0) {
        int n = threadIdx.x;
        float dt  = expf(logdt[n]);
        float dAr = -dt * log1pf(expf(A[2 * n]));
        float dAi = dt * A[2 * n + 1];
        float e1 = expf(dAr);
        lamtab[n * 4 + 0] = make_float2(e1 * cosf(dAi), e1 * sinf(dAi));
        float e16 = expf(16.f * dAr);
        lamtab[n * 4 + 1] = make_float2(e16 * cosf(16.f * dAi), e16 * sinf(16.f * dAi));
        float e128 = expf(128.f * dAr);
        lamtab[n * 4 + 2] = make_float2(e128 * cosf(128.f * dAi), e128 * sinf(128.f * dAi));
        lamtab[n * 4 + 3] = make_float2(dAr, dAi);
    }
}

// ---------------------------------------------------------------------------
// GEMM1 (fused transpose+cast + seg-summary epilogue):
//   xb_t[b][l][n] = sum_c x[b][c][l] * W1[n][c]
//   sums[b][n][seg] = sum_{l=0..127} lambda_n^(127-l) * xb_t[seg*128+l][n]
// 128l x 128n tile, BK=64, 4 waves (2x2), 4x4 16x16x32 MFMA per wave.
// A staged via register transpose into XOR-swizzled fragment-order LDS.
// ---------------------------------------------------------------------------
__global__ __launch_bounds__(256) void gemm1(
        const float* __restrict__ X, const __hip_bfloat16* __restrict__ W1,
        const float2* __restrict__ lamtab,
        __hip_bfloat16* __restrict__ XBT, float2* __restrict__ sums)
{
    __shared__ __hip_bfloat16 Abuf[16 * 512];
    __shared__ __hip_bfloat16 Bbuf[16 * 512];

    const int t = threadIdx.x, lane = t & 63, wave = t >> 6;
    const int wr = wave >> 1, wc = wave & 1;
    const int lm = lane & 15, lq = lane >> 4;
    const int seg = blockIdx.y;
    const int row0 = seg * 128;            // l
    const int col0 = blockIdx.x * 128;     // n
    const int b = blockIdx.z;
    const float* Xb = X + (size_t)b * KD * L_SEQ;

    // A-staging role: thread owns c-block of 8 (one LDS slot) x 4 l's
    const int c8  = t >> 5;        // 0..7
    const int l4  = (t & 31) * 4;  // 0..124
    const int s_w = c8 >> 2;       // k-half
    const int lq_w = c8 & 3;

    f32x4 acc[4][4];
#pragma unroll
    for (int i = 0; i < 4; ++i)
#pragma unroll
        for (int j = 0; j < 4; ++j) acc[i][j] = {0.f, 0.f, 0.f, 0.f};

    for (int k0 = 0; k0 < KD; k0 += 64) {
        // B tile (W1, k-contig) via async 16B direct-to-LDS
#pragma unroll
        for (int i = 0; i < 4; ++i) {
            int jb = wave * 4 + i, ct = jb >> 1, sB = jb & 1;
            const __hip_bfloat16* g =
                W1 + (size_t)(col0 + ct * 16 + lm) * KD + k0 + sB * 32 + lq * 8;
            async_ld16(g, &Bbuf[jb * 512 + lane * 8]);
        }
        // A tile: load x fp32 [c][l], transpose+cast into swizzled frag order
        float4 xv[8];
#pragma unroll
        for (int i = 0; i < 8; ++i)
            xv[i] = *(const float4*)(Xb + (size_t)(k0 + c8 * 8 + i) * L_SEQ + row0 + l4);
#pragma unroll
        for (int j = 0; j < 4; ++j) {
            int l = l4 + j;
            int rt = l >> 4, lmW = l & 15;
            union { __hip_bfloat16 h[8]; uint4 u; } pk;
#pragma unroll
            for (int i = 0; i < 8; ++i) {
                const float* f = (const float*)&xv[i];
                pk.h[i] = __float2bfloat16(f[j]);
            }
            int slot = (lmW ^ rt ^ (s_w << 3)) + 16 * lq_w;
            *(uint4*)&Abuf[(rt * 2 + s_w) * 512 + slot * 8] = pk.u;
        }
        __syncthreads();
#pragma unroll
        for (int s = 0; s < 2; ++s) {
            bf16x8 af[4], bfr[4];
#pragma unroll
            for (int i = 0; i < 4; ++i) {
                int rt = wr * 4 + i;
                int slot = (lm ^ rt ^ (s << 3)) + 16 * lq;
                af[i] = *(const bf16x8*)&Abuf[(rt * 2 + s) * 512 + slot * 8];
            }
#pragma unroll
            for (int j = 0; j < 4; ++j)
                bfr[j] = *(const bf16x8*)&Bbuf[((wc * 4 + j) * 2 + s) * 512 + lane * 8];
#pragma unroll
            for (int i = 0; i < 4; ++i)
#pragma unroll
                for (int j = 0; j < 4; ++j)
                    acc[i][j] = __builtin_amdgcn_mfma_f32_16x16x32_bf16(
                        af[i], bfr[j], acc[i][j], 0, 0, 0);
        }
        __syncthreads();
    }

    // ---- write xb_t (bf16)
    __hip_bfloat16* Db = XBT + (size_t)b * L_SEQ * KD;
#pragma unroll
    for (int i = 0; i < 4; ++i) {
        int r0 = row0 + wr * 64 + i * 16 + lq * 4;
#pragma unroll
        for (int j = 0; j < 4; ++j) {
            int c = col0 + wc * 64 + j * 16 + lm;
#pragma unroll
            for (int r = 0; r < 4; ++r)
                Db[(size_t)(r0 + r) * KD + c] = __float2bfloat16(acc[i][j][r]);
        }
    }

    // ---- seg summaries: sum_l lambda^(127-l) * acc
    // As r descends (l descends), exponent 127-l ASCENDS -> step weight by +lambda.
    float2 par[4];
#pragma unroll
    for (int j = 0; j < 4; ++j) {
        int n = col0 + wc * 64 + j * 16 + lm;
        float2 dA  = lamtab[n * 4 + 3];
        float2 lam = lamtab[n * 4 + 0];
        float m1r = lam.x, m1i = lam.y;      // lambda (FIXED: was lambda^-1)
        float sr = 0.f, si = 0.f;
#pragma unroll
        for (int i = 0; i < 4; ++i) {
            int lbase = wr * 64 + i * 16 + lq * 4;
            float p = (float)(127 - lbase - 3);
            float er = expf(dA.x * p);
            float wrr = er * cosf(dA.y * p), wii = er * sinf(dA.y * p);
            for (int r = 3; r >= 0; --r) {
                float v = acc[i][j][r];
                sr += wrr * v; si += wii * v;
                float nr = wrr * m1r - wii * m1i;
                float ni = wrr * m1i + wii * m1r;
                wrr = nr; wii = ni;
            }
        }
        sr += __shfl_xor(sr, 16); si += __shfl_xor(si, 16);
        sr += __shfl_xor(sr, 32); si += __shfl_xor(si, 32);
        par[j] = make_float2(sr, si);
    }
    float2* ssum = (float2*)Bbuf;   // reuse LDS (all waves past final sync)
    if (wr == 0 && lq == 0) {
#pragma unroll
        for (int j = 0; j < 4; ++j) ssum[wc * 64 + j * 16 + lm] = par[j];
    }
    __syncthreads();
    if (wr == 1 && lq == 0) {
#pragma unroll
        for (int j = 0; j < 4; ++j) {
            float2 o = ssum[wc * 64 + j * 16 + lm];
            int n = col0 + wc * 64 + j * 16 + lm;
            sums[((size_t)b * KD + n) * 64 + seg] =
                make_float2(par[j].x + o.x, par[j].y + o.y);
        }
    }
}

// ---------------------------------------------------------------------------
// scan_carry: per (b,n) wave-scan 64 inclusive seg summaries -> exclusive carries
// ---------------------------------------------------------------------------
__global__ __launch_bounds__(64) void scan_carry(
        const float2* __restrict__ lamtab, float2* __restrict__ sums) {
    const int lane = threadIdx.x;
    const int b = blockIdx.x >> 8, n = blockIdx.x & 255;
    float2 m = lamtab[n * 4 + 2];   // lambda^128
    float mr = m.x, mi = m.y;
    float2 s = sums[((size_t)b * KD + n) * 64 + lane];
    float vr = s.x, vi = s.y;
#pragma unroll
    for (int d = 1; d < 64; d <<= 1) {
        float ur = __shfl_up(vr, (unsigned)d);
        float ui = __shfl_up(vi, (unsigned)d);
        if (lane >= d) {
            float tr = mr * ur - mi * ui + vr;
            float ti = mr * ui + mi * ur + vi;
            vr = tr; vi = ti;
        }
        float m2r = mr * mr - mi * mi;
        float m2i = 2.0f * mr * mi;
        mr = m2r; mi = m2i;
    }
    float cr = __shfl_up(vr, 1u), ci = __shfl_up(vi, 1u);
    if (lane == 0) { cr = 0.f; ci = 0.f; }
    sums[((size_t)b * KD + n) * 64 + lane] = make_float2(cr, ci);
}

// ---------------------------------------------------------------------------
// scan_apply: in-place y = Re(scan) on xb_t, vectorized 8n/thread, 16l/thread.
// Block = one (b,seg): 8 sub-chunks x 32 n-groups. 3-phase block scan.
// ---------------------------------------------------------------------------
__global__ __launch_bounds__(256) void scan_apply(
        __hip_bfloat16* __restrict__ XBT, const float2* __restrict__ lamtab,
        const float2* __restrict__ sums)
{
    __shared__ float2 sl[8][258];
    const int t = threadIdx.x;
    const int sub = t >> 5, n0 = (t & 31) * 8;
    const int seg = blockIdx.x, b = blockIdx.y;
    __hip_bfloat16* base = XBT + ((size_t)b * L_SEQ + seg * 128 + sub * 16) * KD + n0;

    float2 lam[8];
#pragma unroll
    for (int k = 0; k < 8; ++k) lam[k] = lamtab[(n0 + k) * 4];

    uint4 xv[16];
    float sr[8], si[8];
#pragma unroll
    for (int k = 0; k < 8; ++k) { sr[k] = 0.f; si[k] = 0.f; }

    // phase 1: local scan of 16 l's (x cached in regs)
#pragma unroll
    for (int l = 0; l < 16; ++l) {
        xv[l] = *(const uint4*)(base + (size_t)l * KD);
        const __hip_bfloat16* xs = (const __hip_bfloat16*)&xv[l];
#pragma unroll
        for (int k = 0; k < 8; ++k) {
            float v = __bfloat162float(xs[k]);
            float nr = lam[k].x * sr[k] - lam[k].y * si[k] + v;
            float ni = lam[k].x * si[k] + lam[k].y * sr[k];
            sr[k] = nr; si[k] = ni;
        }
    }
#pragma unroll
    for (int k = 0; k < 8; ++k) sl[sub][n0 + k] = make_float2(sr[k], si[k]);
    __syncthreads();

    // phase 2: per-n scan across the 8 sub-chunks (thread t owns n=t)
    {
        int n = t;
        float2 m16 = lamtab[n * 4 + 1];
        float2 c = sums[((size_t)b * KD + n) * 64 + seg];
        float cr = c.x, ci = c.y;
#pragma unroll
        for (int s2 = 0; s2 < 8; ++s2) {
            float2 loc = sl[s2][n];
            sl[s2][n] = make_float2(cr, ci);     // exclusive carry for sub-chunk
            float nr = m16.x * cr - m16.y * ci + loc.x;
            float ni = m16.x * ci + m16.y * cr + loc.y;
            cr = nr; ci = ni;
        }
    }
    __syncthreads();

    // phase 3: rescan with carry, write y = Re(s) back (bf16, 16B stores)
#pragma unroll
    for (int k = 0; k < 8; ++k) {
        float2 c = sl[sub][n0 + k];
        sr[k] = c.x; si[k] = c.y;
    }
#pragma unroll
    for (int l = 0; l < 16; ++l) {
        const __hip_bfloat16* xs = (const __hip_bfloat16*)&xv[l];
        union { __hip_bfloat16 h[8]; uint4 u; } yv;
#pragma unroll
        for (int k = 0; k < 8; ++k) {
            float v = __bfloat162float(xs[k]);
            float nr = lam[k].x * sr[k] - lam[k].y * si[k] + v;
            float ni = lam[k].x * si[k] + lam[k].y * sr[k];
            sr[k] = nr; si[k] = ni;
            yv.h[k] = __float2bfloat16(nr);
        }
        *(uint4*)(base + (size_t)l * KD) = yv.u;
    }
}

// ---------------------------------------------------------------------------
// GEMM2: out[b][d][l] = sum_n Cbf[d][n] * y_t[b][l][n]
// ---------------------------------------------------------------------------
__global__ __launch_bounds__(256) void gemm2(
        const __hip_bfloat16* __restrict__ Ag,    // Cbf [256][256]
        const __hip_bfloat16* __restrict__ Bg,    // y_t [B][L][256]
        float* __restrict__ Dg)                   // out [B][256][L]
{
    __shared__ __hip_bfloat16 Abuf[16 * 512];
    __shared__ __hip_bfloat16 Bbuf[16 * 512];

    const int t = threadIdx.x, lane = t & 63, wave = t >> 6;
    const int wr = wave >> 1, wc = wave & 1;
    const int row0 = blockIdx.y * 128, col0 = blockIdx.x * 128;
    const int lm = lane & 15, lq = lane >> 4;
    const __hip_bfloat16* Bb = Bg + (size_t)blockIdx.z * L_SEQ * KD;
    float* Db = Dg + (size_t)blockIdx.z * KD * L_SEQ;

    f32x4 acc[4][4];
#pragma unroll
    for (int i = 0; i < 4; ++i)
#pragma unroll
        for (int j = 0; j < 4; ++j) acc[i][j] = {0.f, 0.f, 0.f, 0.f};

    for (int k0 = 0; k0 < KD; k0 += 64) {
#pragma unroll
        for (int i = 0; i < 8; ++i) {
            int idx = wave * 8 + i;
            if (idx < 16) {
                int rt = idx >> 1, s = idx & 1;
                const __hip_bfloat16* g =
                    Ag + (size_t)(row0 + rt * 16 + lm) * KD + k0 + s * 32 + lq * 8;
                async_ld16(g, &Abuf[idx * 512 + lane * 8]);
            } else {
                int jb = idx - 16, ct = jb >> 1, s = jb & 1;
                const __hip_bfloat16* g =
                    Bb + (size_t)(col0 + ct * 16 + lm) * KD + k0 + s * 32 + lq * 8;
                async_ld16(g, &Bbuf[jb * 512 + lane * 8]);
            }
        }
        __syncthreads();
#pragma unroll
        for (int s = 0; s < 2; ++s) {
            bf16x8 af[4], bfr[4];
#pragma unroll
            for (int i = 0; i < 4; ++i)
                af[i] = *(const bf16x8*)&Abuf[((wr * 4 + i) * 2 + s) * 512 + lane * 8];
#pragma unroll
            for (int j = 0; j < 4; ++j)
                bfr[j] = *(const bf16x8*)&Bbuf[((wc * 4 + j) * 2 + s) * 512 + lane * 8];
#pragma unroll
            for (int i = 0; i < 4; ++i)
#pragma unroll
                for (int j = 0; j < 4; ++j)
                    acc[i][j] = __builtin_amdgcn_mfma_f32_16x16x32_bf16(
                        af[i], bfr[j], acc[i][j], 0, 0, 0);
        }
        __syncthreads();
    }

#pragma unroll
    for (int i = 0; i < 4; ++i) {
        int r0 = row0 + wr * 64 + i * 16 + lq * 4;
#pragma unroll
        for (int j = 0; j < 4; ++j) {
            int c = col0 + wc * 64 + j * 16 + lm;
#pragma unroll
            for (int r = 0; r < 4; ++r)
                Db[(size_t)(r0 + r) * L_SEQ + c] = acc[i][j][r];
        }
    }
}

// ---------------------------------------------------------------------------
// Launch
// ---------------------------------------------------------------------------
extern "C" void kernel_launch(void* const* d_in, const int* in_sizes, int n_in,
                              void* d_out, int out_size, void* d_ws, size_t ws_size,
                              hipStream_t stream) {
    const float* x      = (const float*)d_in[0];
    const float* A      = (const float*)d_in[1];
    const float* B      = (const float*)d_in[2];
    const float* log_dt = (const float*)d_in[3];
    const float* C      = (const float*)d_in[4];
    float* out = (float*)d_out;

    char* ws = (char*)d_ws;
    __hip_bfloat16* W1bf = (__hip_bfloat16*)(ws);                  // 128 KB
    __hip_bfloat16* Cbf  = (__hip_bfloat16*)(ws + (128 << 10));    // 128 KB
    float2*         lamtab = (float2*)(ws + (256 << 10));          // 8 KB
    float2*         sums = (float2*)(ws + (320 << 10));            // 1 MB
    __hip_bfloat16* xb_t = (__hip_bfloat16*)(ws + ((size_t)2 << 20)); // 32 MB

    prep<<<256, 256, 0, stream>>>(B, log_dt, C, A, W1bf, Cbf, lamtab);
    gemm1<<<dim3(2, 64, BATCH), 256, 0, stream>>>(x, W1bf, lamtab, xb_t, sums);
    scan_carry<<<BATCH * KD, 64, 0, stream>>>(lamtab, sums);
    scan_apply<<<dim3(64, BATCH), 256, 0, stream>>>(xb_t, lamtab, sums);
    gemm2<<<dim3(L_SEQ / 128, KD / 128, BATCH), 256, 0, stream>>>(Cbf, xb_t, out);
}